// Round 1
// baseline (265.321 us; speedup 1.0000x reference)
//
#include <hip/hip_runtime.h>
#include <math.h>

// Problem constants (fixed by setup_inputs)
#define BB   32
#define CC   256
#define LL   4096
#define SS   8
#define CS   32
#define NT   256                 // threads per block
#define F4_ROW (LL / 4)          // 1024 float4 per row
#define F4_THR (F4_ROW / NT)     // 4 float4 per thread

typedef float f4 __attribute__((ext_vector_type(4)));

__device__ __forceinline__ float gelu_exact(float x) {
    // exact gelu: x * 0.5 * (1 + erf(x / sqrt(2)))
    return 0.5f * x * (1.0f + erff(x * 0.70710678118654752440f));
}

// Workgroup barrier that drains ONLY LDS (lgkmcnt). Unlike __syncthreads(),
// it does NOT wait vmcnt(0) -> global prefetch loads and epilogue stores stay
// in flight across it. All cross-thread data here flows through LDS, so
// lgkmcnt(0)+s_barrier is sufficient. Memory clobbers pin ordering.
__device__ __forceinline__ void lds_barrier() {
    asm volatile("s_waitcnt lgkmcnt(0)" ::: "memory");
    __builtin_amdgcn_s_barrier();
    asm volatile("" ::: "memory");
}

__global__ __launch_bounds__(NT, 4)
void hdconv_encoder_kernel(const float* __restrict__ inp,
                           const float* __restrict__ conv_w,   // [S,3,CS]
                           const float* __restrict__ conv_b,   // [S,CS]
                           const float* __restrict__ ln_g,     // [L]
                           const float* __restrict__ ln_b,     // [L]
                           const float* __restrict__ pw_w,     // [C]
                           const float* __restrict__ pw_b,     // [C]
                           float* __restrict__ out) {
    // Tiny double-buffered LDS. Position order is f = t + NT*k, i.e. (k major,
    // wave w = t>>6 minor). Flatten kw = k*4 + w in [0,16).
    //   eW[p][1+kw] = s[last elem of (w,k) chunk]   (written by lane 63)
    //   eW[p][0]    = 0 sentinel (position -1)
    //   eX[p][kw]   = s[first elem of (w,k) chunk]  (written by lane 0)
    //   eX[p][16]   = 0 sentinel (position L)
    // Reader lane 0 of (w,k) wants s[4f-1] = eW[p][kw]  (previous chunk's last)
    // Reader lane 63 of (w,k) wants s[4f+4] = eX[p][kw+1] (next chunk's first)
    __shared__ float eW[2][17];
    __shared__ float eX[2][17];
    __shared__ float red[2][8];   // per-wave {sum, sumsq}, double-buffered

    const int t    = threadIdx.x;
    const int blk  = blockIdx.x;      // [0, B*CS)
    const int b    = blk >> 5;        // batch
    const int c    = blk & 31;        // channel within group (block-uniform)
    const int lane = t & 63;
    const int wave = t >> 6;

    if (t == 0) {
        eW[0][0]  = 0.0f; eW[1][0]  = 0.0f;
        eX[0][16] = 0.0f; eX[1][16] = 0.0f;
    }

    // y_{i-1} for this thread's 16 positions (0 before group 0)
    float y[16];
#pragma unroll
    for (int j = 0; j < 16; ++j) y[j] = 0.0f;

    // LayerNorm gamma/beta are indexed by position l -> load once, reuse x8
    float4 g4[F4_THR], e4[F4_THR];
    {
        const float4* gp = (const float4*)ln_g;
        const float4* ep = (const float4*)ln_b;
#pragma unroll
        for (int k = 0; k < F4_THR; ++k) {
            g4[k] = gp[t + NT * k];
            e4[k] = ep[t + NT * k];
        }
    }

    // Load x_0 (the only load whose latency is exposed; 1/8 of the chain)
    f4 x4[F4_THR];
    {
        const f4* xrow = (const f4*)(inp + ((size_t)(b * CC + c)) * LL);
#pragma unroll
        for (int k = 0; k < F4_THR; ++k) x4[k] = xrow[t + NT * k];
    }

    // Prologue edges for i=0: y_{-1}=0 so s = x
#pragma unroll
    for (int k = 0; k < F4_THR; ++k) {
        const int kw = k * 4 + wave;
        if (lane == 63) eW[0][1 + kw] = x4[k].w;
        if (lane == 0)  eX[0][kw]     = x4[k].x;
    }
    lds_barrier();

    for (int i = 0; i < SS; ++i) {
        const int p  = i & 1;
        const int ch = i * CS + c;                        // global channel

        // ---- prefetch x_{i+1}: issued first, used one full iteration later.
        // lds_barrier() does not drain vmcnt, so these stay in flight across
        // the barrier; conv+reduce+epilogue (~1k VALU inst) hide the latency.
        f4 xn4[F4_THR];
        if (i + 1 < SS) {
            const f4* xn = (const f4*)(inp + ((size_t)(b * CC + ch + CS)) * LL);
#pragma unroll
            for (int k = 0; k < F4_THR; ++k) xn4[k] = xn[t + NT * k];
        }

        // block-uniform per-(group, c) params -> scalar loads
        const float w0 = conv_w[i * 96 + 0 * CS + c];
        const float w1 = conv_w[i * 96 + 1 * CS + c];
        const float w2 = conv_w[i * 96 + 2 * CS + c];
        const float bb = conv_b[i * CS + c];

        // ---- 3-tap depthwise conv via shfl halos + LN partial sums ----
        float lsum = 0.0f, lsq = 0.0f;
#pragma unroll
        for (int k = 0; k < F4_THR; ++k) {
            const int kw = k * 4 + wave;
            const float s0 = x4[k].x + y[4 * k + 0];
            const float s1 = x4[k].y + y[4 * k + 1];
            const float s2 = x4[k].z + y[4 * k + 2];
            const float s3 = x4[k].w + y[4 * k + 3];
            // neighbor values: same floats as before, moved by shfl not LDS
            float sm1 = __shfl_up(s3, 1, 64);    // lane l-1's s3 == s[4f-1]
            float sp4 = __shfl_down(s0, 1, 64);  // lane l+1's s0 == s[4f+4]
            if (lane == 0)  sm1 = eW[p][kw];
            if (lane == 63) sp4 = eX[p][kw + 1];
            const float y0 = fmaf(w0, sm1, fmaf(w1, s0, fmaf(w2, s1, bb)));
            const float y1 = fmaf(w0, s0,  fmaf(w1, s1, fmaf(w2, s2, bb)));
            const float y2 = fmaf(w0, s1,  fmaf(w1, s2, fmaf(w2, s3, bb)));
            const float y3 = fmaf(w0, s2,  fmaf(w1, s3, fmaf(w2, sp4, bb)));
            y[4 * k + 0] = y0; y[4 * k + 1] = y1;
            y[4 * k + 2] = y2; y[4 * k + 3] = y3;
            lsum += (y0 + y1) + (y2 + y3);
            lsq  += fmaf(y0, y0, fmaf(y1, y1, fmaf(y2, y2, y3 * y3)));
        }

        // ---- wave reduce, cross-wave partials to LDS ----
#pragma unroll
        for (int off = 32; off > 0; off >>= 1) {
            lsum += __shfl_down(lsum, off, 64);
            lsq  += __shfl_down(lsq,  off, 64);
        }
        if (lane == 0) { red[p][wave * 2] = lsum; red[p][wave * 2 + 1] = lsq; }

        // ---- edges for iteration i+1 into the other buffer (prefetched x + new y)
        if (i + 1 < SS) {
#pragma unroll
            for (int k = 0; k < F4_THR; ++k) {
                const int kw = k * 4 + wave;
                if (lane == 63) eW[p ^ 1][1 + kw] = xn4[k].w + y[4 * k + 3];
                if (lane == 0)  eX[p ^ 1][kw]     = xn4[k].x + y[4 * k + 0];
            }
        }

        // ONE barrier per group: publishes red[p] and next-iteration edges.
        lds_barrier();

        // every thread folds the 4 wave-partials itself (no t==0 + 3rd barrier)
        const float sum = (red[p][0] + red[p][2]) + (red[p][4] + red[p][6]);
        const float sq  = (red[p][1] + red[p][3]) + (red[p][5] + red[p][7]);
        const float mean = sum * (1.0f / LL);
        const float var  = sq * (1.0f / LL) - mean * mean;
        const float inv  = rsqrtf(var + 1e-6f);

        // ---- normalize + pointwise scale/bias + exact gelu + residual ----
        const float pw = pw_w[ch];
        const float pb = pw_b[ch];
        f4* orow = (f4*)(out + ((size_t)(b * CC + ch)) * LL);
#pragma unroll
        for (int k = 0; k < F4_THR; ++k) {
            f4 o;
            float n;
            n   = fmaf((y[4 * k + 0] - mean) * inv, g4[k].x, e4[k].x);
            o.x = x4[k].x + gelu_exact(fmaf(n, pw, pb));
            n   = fmaf((y[4 * k + 1] - mean) * inv, g4[k].y, e4[k].y);
            o.y = x4[k].y + gelu_exact(fmaf(n, pw, pb));
            n   = fmaf((y[4 * k + 2] - mean) * inv, g4[k].z, e4[k].z);
            o.z = x4[k].z + gelu_exact(fmaf(n, pw, pb));
            n   = fmaf((y[4 * k + 3] - mean) * inv, g4[k].w, e4[k].w);
            o.w = x4[k].w + gelu_exact(fmaf(n, pw, pb));
            // write-once stream: keep it out of L3 so the input stays resident
            __builtin_nontemporal_store(o, &orow[t + NT * k]);
        }

        if (i + 1 < SS) {
#pragma unroll
            for (int k = 0; k < F4_THR; ++k) x4[k] = xn4[k];
        }
    }
}

extern "C" void kernel_launch(void* const* d_in, const int* in_sizes, int n_in,
                              void* d_out, int out_size, void* d_ws, size_t ws_size,
                              hipStream_t stream) {
    const float* inp    = (const float*)d_in[0];
    const float* conv_w = (const float*)d_in[1];
    const float* conv_b = (const float*)d_in[2];
    const float* ln_g   = (const float*)d_in[3];
    const float* ln_b   = (const float*)d_in[4];
    const float* pw_w   = (const float*)d_in[5];
    const float* pw_b   = (const float*)d_in[6];
    float* out = (float*)d_out;

    dim3 grid(BB * CS);   // 1024 blocks: one per (batch, within-group channel) chain
    dim3 block(NT);
    hdconv_encoder_kernel<<<grid, block, 0, stream>>>(
        inp, conv_w, conv_b, ln_g, ln_b, pw_w, pw_b, out);
}